// Round 10
// baseline (140.628 us; speedup 1.0000x reference)
//
#include <hip/hip_runtime.h>

#define TT    2048
#define SS    512
#define NB    16
#define EPEN  0.60653065971263342f   // exp(-0.5)
#define NCHUNK 64
#define CLEN   32

typedef __attribute__((ext_vector_type(4))) float  floatx4;
typedef __attribute__((ext_vector_type(8))) short  bf16x8;

__device__ __forceinline__ ushort f2bf(float x) {   // RNE fp32 -> bf16
  unsigned u = __float_as_uint(x);
  u += 0x7fffu + ((u >> 16) & 1u);
  return (ushort)(u >> 16);
}

__device__ __forceinline__ unsigned pack2(ushort a, ushort b) {
  return (unsigned)a | ((unsigned)b << 16);
}

// ---------------- kernel 0: W -> MFMA-fragment order (W only) -------------
// Wt2[(((colt*16+kt)*16+rc)*4+q)*8+e] = bf16(W[kt*32+q*8+e][colt*16+rc])
// A-fragments are now staged inside proj (block-local; no global round-trip).
__global__ __launch_bounds__(256) void prep_kernel(
    const float* __restrict__ Wa, const float* __restrict__ Ws,
    const float* __restrict__ Wst, ushort* __restrict__ Wt2)
{
  int fid = blockIdx.x * 256 + threadIdx.x;   // 21504 B-frags
  if (fid >= 21504) return;
  const int q = fid & 3, rc = (fid >> 2) & 15, kt = (fid >> 6) & 15, colt = fid >> 10;
  const int col = colt * 16 + rc;
  const int kbase = kt * 32 + q * 8;
  ushort h[8];
  #pragma unroll
  for (int e = 0; e < 8; ++e) {
    const int k = kbase + e;
    float v;
    if (col < 288)      v = Wa [(size_t)k * 288 + col];
    else if (col < 320) v = Ws [(size_t)k * 32  + (col - 288)];
    else                v = Wst[(size_t)k * 16  + (col - 320)];
    h[e] = f2bf(v);
  }
  uint4 o = make_uint4(pack2(h[0], h[1]), pack2(h[2], h[3]),
                       pack2(h[4], h[5]), pack2(h[6], h[7]));
  *(uint4*)(Wt2 + (size_t)fid * 8) = o;
}

// ---------------- kernel A: MFMA GEMM + softmax -> coef --------------------
// 129 blocks x 16 rows, 8 waves (512 thr). A-fragments staged block-locally:
// s_i rows -> bf16 fragment layout in LDS (coalesced float4 reads, same f2bf
// as before -> bit-identical fragments). B pre-laid-out in global (L2-hot).
// Wave (kh, ng): kh owns k-tiles kh*8.., ng owns n-tiles {ng, ng+4, ...}.
// 1-deep pipeline on A(LDS)+B(global); no barrier in k-loop; k-halves merge
// in LDS. MFMA order identical to round-9 -> bit-identical output.
__global__ __launch_bounds__(512) void proj_kernel(
    const float* __restrict__ s_i,
    const ushort* __restrict__ Wt2,
    const int*   __restrict__ actions,
    float4*      __restrict__ coef)
{
  __shared__ __align__(16) ushort At[8192];   // A fragments: 16 kt x 16 rc x 4 q x 8e
  __shared__ float lg[16][346];               // stride 346: 2-way bank aliasing (free)

  const int tid  = threadIdx.x;
  const int wave = tid >> 6, lane = tid & 63;
  const int q = lane >> 4, rc = lane & 15;
  const int row0 = blockIdx.x * 16;

  // ---- stage A: 1024 fragment-units, 2 per thread (coalesced 32B reads)
  #pragma unroll
  for (int u = 0; u < 2; ++u) {
    const int uid = tid + u * 512;
    const int qq = uid & 3, rr = (uid >> 2) & 15, kt = uid >> 6;
    int row = row0 + rr; if (row > TT) row = TT;
    const float* src = s_i + (size_t)row * SS + kt * 32 + qq * 8;
    float4 v0 = *(const float4*)src;
    float4 v1 = *(const float4*)(src + 4);
    uint4 o = make_uint4(pack2(f2bf(v0.x), f2bf(v0.y)),
                         pack2(f2bf(v0.z), f2bf(v0.w)),
                         pack2(f2bf(v1.x), f2bf(v1.y)),
                         pack2(f2bf(v1.z), f2bf(v1.w)));
    *(uint4*)(At + (size_t)uid * 8) = o;
  }
  __syncthreads();

  const int kh = wave >> 2;                  // k-half
  const int ng = wave & 3;                   // n-group
  const int ntiles = (ng == 0) ? 6 : 5;
  const int kt0 = kh * 8;

  const ushort* aBase = At  + rc * 32 + q * 8;          // LDS
  const ushort* bBase = Wt2 + rc * 32 + q * 8;          // global (L2-hot)

  floatx4 acc[6];
  #pragma unroll
  for (int j = 0; j < 6; ++j) acc[j] = (floatx4)(0.f);

  bf16x8 aC, aN, bC[6], bN[6];

  // ---- prologue: load k-tile kt0 fragments
  aC = *(const bf16x8*)(aBase + kt0 * 512);
  #pragma unroll
  for (int j = 0; j < 6; ++j) {
    if (j < ntiles) {
      const int colt = ng + 4 * j;
      bC[j] = *(const bf16x8*)(bBase + (size_t)colt * 8192 + kt0 * 512);
    }
  }

  #pragma unroll
  for (int kk = 0; kk < 8; ++kk) {
    const int kt = kt0 + kk;
    // ---- issue next k-tile's loads (stay in flight under the MFMAs)
    if (kk < 7) {
      aN = *(const bf16x8*)(aBase + (kt + 1) * 512);
      #pragma unroll
      for (int j = 0; j < 6; ++j) {
        if (j < ntiles) {
          const int colt = ng + 4 * j;
          bN[j] = *(const bf16x8*)(bBase + (size_t)colt * 8192 + (kt + 1) * 512);
        }
      }
    }
    #pragma unroll
    for (int j = 0; j < 6; ++j) {
      if (j < ntiles)
        acc[j] = __builtin_amdgcn_mfma_f32_16x16x32_bf16(aC, bC[j], acc[j], 0, 0, 0);
    }
    // ---- rotate pipeline (full unroll -> pure register renames)
    aC = aN;
    #pragma unroll
    for (int j = 0; j < 6; ++j) {
      if (j < ntiles) bC[j] = bN[j];
    }
  }

  // ---- merge k-halves through LDS (C/D layout: row = q*4+reg, col = rc)
  if (kh == 0) {
    #pragma unroll
    for (int j = 0; j < 6; ++j) {
      if (j < ntiles) {
        const int colt = ng + 4 * j;
        #pragma unroll
        for (int reg = 0; reg < 4; ++reg)
          lg[q * 4 + reg][colt * 16 + rc] = acc[j][reg];
      }
    }
  }
  __syncthreads();
  if (kh == 1) {
    #pragma unroll
    for (int j = 0; j < 6; ++j) {
      if (j < ntiles) {
        const int colt = ng + 4 * j;
        #pragma unroll
        for (int reg = 0; reg < 4; ++reg)
          lg[q * 4 + reg][colt * 16 + rc] += acc[j][reg];
      }
    }
  }
  __syncthreads();

  // ---- softmax epilogue: 16 rows x 16 b, threads 0..255
  if (tid < 256) {
    const int r = tid >> 4, b = tid & 15;
    const int row = row0 + r;
    if (row < TT) {
      float m = -3.4e38f;
      #pragma unroll
      for (int a = 0; a < 18; ++a) m = fmaxf(m, lg[r][b * 18 + a]);
      float sum = 0.f;
      #pragma unroll
      for (int a = 0; a < 18; ++a) sum += __expf(lg[r][b * 18 + a] - m);
      int act = actions[row];
      float aprob = __expf(lg[r][b * 18 + act] - m) / sum;

      float x0 = lg[r][288 + 2 * b], x1 = lg[r][288 + 2 * b + 1];
      float mm = fmaxf(x0, x1);
      float e0 = __expf(x0 - mm), e1 = __expf(x1 - mm);
      float inv = 1.f / (e0 + e1);

      float ms = -3.4e38f;
      #pragma unroll
      for (int j = 0; j < 16; ++j) ms = fmaxf(ms, lg[r][320 + j]);
      float ssum = 0.f;
      #pragma unroll
      for (int j = 0; j < 16; ++j) ssum += __expf(lg[r][320 + j] - ms);
      float stp = __expf(lg[r][320 + b] - ms) / ssum;

      coef[(size_t)row * NB + b] = make_float4(e0 * inv, e1 * inv, stp, aprob);
    } else if (row == TT) {
      // virtual step 2048: A = I, "action" prob = stop0 prob of row T
      float x0 = lg[r][288 + 2 * b], x1 = lg[r][288 + 2 * b + 1];
      float mm = fmaxf(x0, x1);
      float e0 = __expf(x0 - mm), e1 = __expf(x1 - mm);
      coef[(size_t)TT * NB + b] = make_float4(1.f, 0.f, 0.f, e0 / (e0 + e1));
    }
  }
}

// ---------------- kernel BC: fused pass1 + pass2 (one block, 512 thr) -----
// Phase B (pass1): 64 chunk chains, 32-wide x 2 rounds; G matrices land in
// LDS (Mlds, 64 KB) instead of global; Wws still global (read L2-hot in
// phase D). Chain math byte-identical to the standalone pass1.
// Phase C (pass2 phase 1): wave-0 serial chain; M prefetch regs now fill
// from LDS (ds_read_b128) - same depth-8 named-reg structure, same bits.
// Phase D: 2048 parallel log terms; thread 0 adds ln2*Ktot + U0.
__global__ __launch_bounds__(512) void pass12_kernel(
    const float4* __restrict__ coef,
    float* __restrict__ Wws,
    float* __restrict__ out)
{
  __shared__ float Mlds[NCHUNK * 256];   // 64 KB: chunk transfer matrices
  __shared__ float pbuf[NCHUNK][16];     // chunk-start scaled p vectors
  __shared__ float wacc[8];              // per-wave partial log sums

  const int tid = threadIdx.x;
  long long Ktot = 0;                    // only thread 0's value is used

  // ---------------- phase B: pass1 chains (32-wide, 2 rounds) ------------
  for (int round = 0; round < 2; ++round) {
    const int chunk = (tid >> 4) + round * 32;
    const int c = tid & 15;
    const int i0 = chunk * CLEN + 1;

    float G[16];
    #pragma unroll
    for (int r = 0; r < 16; ++r) G[r] = (r == c) ? 1.f : 0.f;

    float4 cfA[16], cfB[16];
    #pragma unroll
    for (int r = 0; r < 16; ++r) cfA[r] = coef[(size_t)i0 * 16 + r];
    #pragma unroll
    for (int r = 0; r < 16; ++r) cfB[r] = coef[(size_t)(i0 + 1) * 16 + r];

#define P1BODY(CUR, NXT, J)                                                  \
    {                                                                        \
      if ((J) + 2 < CLEN) {                                                  \
        _Pragma("unroll")                                                    \
        for (int r = 0; r < 16; ++r)                                         \
          NXT[r] = coef[(size_t)(i0 + (J) + 2) * 16 + r];                    \
      }                                                                      \
      float ta = 0.f, tb = 0.f, tc = 0.f, td = 0.f;                          \
      _Pragma("unroll")                                                      \
      for (int r = 0; r < 4; ++r) {                                          \
        ta = fmaf(CUR[r].y,      G[r],      ta);                             \
        tb = fmaf(CUR[r + 4].y,  G[r + 4],  tb);                             \
        tc = fmaf(CUR[r + 8].y,  G[r + 8],  tc);                             \
        td = fmaf(CUR[r + 12].y, G[r + 12], td);                             \
      }                                                                      \
      float et = EPEN * ((ta + tb) + (tc + td));                             \
      _Pragma("unroll")                                                      \
      for (int r = 0; r < 16; ++r)                                           \
        G[r] = fmaf(CUR[r].x, G[r], CUR[r].z * et);                          \
      float wa = 0.f, wb = 0.f, wc = 0.f, wd = 0.f;                          \
      _Pragma("unroll")                                                      \
      for (int r = 0; r < 4; ++r) {                                          \
        wa = fmaf(CUR[r].w,      G[r],      wa);                             \
        wb = fmaf(CUR[r + 4].w,  G[r + 4],  wb);                             \
        wc = fmaf(CUR[r + 8].w,  G[r + 8],  wc);                             \
        wd = fmaf(CUR[r + 12].w, G[r + 12], wd);                             \
      }                                                                      \
      Wws[(size_t)(chunk * CLEN + (J)) * 16 + c] = (wa + wb) + (wc + wd);    \
    }

    for (int j = 0; j < CLEN; j += 2) {
      P1BODY(cfA, cfB, j);
      P1BODY(cfB, cfA, j + 1);
    }
#undef P1BODY

    #pragma unroll
    for (int r = 0; r < 16; ++r)
      Mlds[chunk * 256 + r * 16 + c] = G[r];
  }
  __syncthreads();   // Mlds + Wws visible block-wide

  // ---------------- phase C: serial chain, wave 0 only --------------------
  if (tid < 64) {
    const int r = tid >> 2, g = tid & 3;     // quad layout: lane = 4r+g
    float pj0 = coef[4 * g + 0].z;
    float pj1 = coef[4 * g + 1].z;
    float pj2 = coef[4 * g + 2].z;
    float pj3 = coef[4 * g + 3].z;

    const int moff = r * 16 + 4 * g;
    // bpermute byte addrs: y_{4g+j} lives in quad (4g+j) -> lane 16g+4j
    const int gb0 = 64 * g, gb1 = gb0 + 16, gb2 = gb0 + 32, gb3 = gb0 + 48;
    int Ecum = 0;

    // prefetch depth 8 (named regs; fills from LDS now)
    float4 mR0 = *(const float4*)&Mlds[0 * 256 + moff];
    float4 mR1 = *(const float4*)&Mlds[1 * 256 + moff];
    float4 mR2 = *(const float4*)&Mlds[2 * 256 + moff];
    float4 mR3 = *(const float4*)&Mlds[3 * 256 + moff];
    float4 mR4 = *(const float4*)&Mlds[4 * 256 + moff];
    float4 mR5 = *(const float4*)&Mlds[5 * 256 + moff];
    float4 mR6 = *(const float4*)&Mlds[6 * 256 + moff];
    float4 mR7 = *(const float4*)&Mlds[7 * 256 + moff];

#define P2BODY(K, MREG, KPF)                                                 \
    {                                                                        \
      if (r == 0)                                                            \
        *(float4*)&pbuf[(K)][4 * g] = make_float4(pj0, pj1, pj2, pj3);       \
      Ktot += 32LL * (long long)Ecum;                                        \
      float part = fmaf(MREG.x, pj0,                                         \
                   fmaf(MREG.y, pj1, fmaf(MREG.z, pj2, MREG.w * pj3)));      \
      if ((KPF) < NCHUNK)                                                    \
        MREG = *(const float4*)&Mlds[(KPF) * 256 + moff];                    \
      /* quad rotate-add: (Pg+Pg+1)+(Pg+2+Pg+3) */                           \
      part += __int_as_float(__builtin_amdgcn_mov_dpp(                       \
          __float_as_int(part), 0x39, 0xF, 0xF, true));  /* quad ror 1 */    \
      part += __int_as_float(__builtin_amdgcn_mov_dpp(                       \
          __float_as_int(part), 0x4E, 0xF, 0xF, true));  /* quad ror 2 */    \
      int ip = __float_as_int(part);                                         \
      float n0 = __int_as_float(__builtin_amdgcn_ds_bpermute(gb0, ip));      \
      float n1 = __int_as_float(__builtin_amdgcn_ds_bpermute(gb1, ip));      \
      float n2 = __int_as_float(__builtin_amdgcn_ds_bpermute(gb2, ip));      \
      float n3 = __int_as_float(__builtin_amdgcn_ds_bpermute(gb3, ip));      \
      float y0 = __int_as_float(__builtin_amdgcn_ds_bpermute(0,   ip));      \
      int eb = (__float_as_int(y0) >> 23) & 255;                             \
      Ecum += eb - 127;                                                      \
      float sc = __int_as_float((254 - eb) << 23);                           \
      pj0 = n0 * sc; pj1 = n1 * sc; pj2 = n2 * sc; pj3 = n3 * sc;            \
    }

    for (int kb = 0; kb < NCHUNK; kb += 8) {
      P2BODY(kb + 0, mR0, kb + 8);
      P2BODY(kb + 1, mR1, kb + 9);
      P2BODY(kb + 2, mR2, kb + 10);
      P2BODY(kb + 3, mR3, kb + 11);
      P2BODY(kb + 4, mR4, kb + 12);
      P2BODY(kb + 5, mR5, kb + 13);
      P2BODY(kb + 6, mR6, kb + 14);
      P2BODY(kb + 7, mR7, kb + 15);
    }
#undef P2BODY
  }
  __syncthreads();

  // ---------------- phase D: 2048 parallel log terms ----------------------
  const int j0 = tid * 4;              // 4 consecutive steps, same chunk
  const int chunk = j0 >> 5;
  float p[16];
  #pragma unroll
  for (int c = 0; c < 16; ++c) p[c] = pbuf[chunk][c];

  float lacc = 0.f;
  #pragma unroll
  for (int jj = 0; jj < 4; ++jj) {
    const float* w = Wws + (size_t)(j0 + jj) * 16;
    float4 w0 = *(const float4*)(w);
    float4 w1 = *(const float4*)(w + 4);
    float4 w2 = *(const float4*)(w + 8);
    float4 w3 = *(const float4*)(w + 12);
    float s0 = fmaf(w0.x, p[0],  fmaf(w0.y, p[1],  fmaf(w0.z, p[2],  w0.w * p[3])));
    float s1 = fmaf(w1.x, p[4],  fmaf(w1.y, p[5],  fmaf(w1.z, p[6],  w1.w * p[7])));
    float s2 = fmaf(w2.x, p[8],  fmaf(w2.y, p[9],  fmaf(w2.z, p[10], w2.w * p[11])));
    float s3 = fmaf(w3.x, p[12], fmaf(w3.y, p[13], fmaf(w3.z, p[14], w3.w * p[15])));
    lacc += __logf((s0 + s1) + (s2 + s3));
  }

  if (tid == 0) {          // U0 term: sum_c coef[c].w * coef[c].z
    float U0 = 0.f;
    #pragma unroll
    for (int c = 0; c < 16; ++c) U0 = fmaf(coef[c].w, coef[c].z, U0);
    lacc += __logf(U0);
  }

  // wave reduce, then 8-entry double sum
  lacc += __shfl_xor(lacc, 1, 64);
  lacc += __shfl_xor(lacc, 2, 64);
  lacc += __shfl_xor(lacc, 4, 64);
  lacc += __shfl_xor(lacc, 8, 64);
  lacc += __shfl_xor(lacc, 16, 64);
  lacc += __shfl_xor(lacc, 32, 64);
  if ((tid & 63) == 0) wacc[tid >> 6] = lacc;
  __syncthreads();
  if (tid == 0) {
    double s = 0.0;
    #pragma unroll
    for (int i = 0; i < 8; ++i) s += (double)wacc[i];
    out[0] = (float)(s + 0.6931471805599453 * (double)Ktot);
  }
}

extern "C" void kernel_launch(void* const* d_in, const int* in_sizes, int n_in,
                              void* d_out, int out_size, void* d_ws, size_t ws_size,
                              hipStream_t stream) {
  const float* s_i = (const float*)d_in[0];
  const float* Wa  = (const float*)d_in[1];
  const float* Ws  = (const float*)d_in[2];
  const float* Wst = (const float*)d_in[3];
  const int*   act = (const int*)d_in[4];

  char* ws = (char*)d_ws;
  float4* coef = (float4*)ws;                        //   524,544 B
  float*  Wws  = (float*)(ws + 524544);              // + 131,072 B
  ushort* Wt2  = (ushort*)(ws + 524544 + 131072);    // + 344,064 B (~1.0 MB)

  prep_kernel  <<<84,  256, 0, stream>>>(Wa, Ws, Wst, Wt2);
  proj_kernel  <<<129, 512, 0, stream>>>(s_i, Wt2, act, coef);
  pass12_kernel<<<1,   512, 0, stream>>>(coef, Wws, (float*)d_out);
}

// Round 11
// 96.885 us; speedup vs baseline: 1.4515x; 1.4515x over previous
//
#include <hip/hip_runtime.h>

#define TT    2048
#define SS    512
#define NB    16
#define EPEN  0.60653065971263342f   // exp(-0.5)
#define NCHUNK 64
#define CLEN   32

typedef __attribute__((ext_vector_type(4))) float  floatx4;
typedef __attribute__((ext_vector_type(8))) short  bf16x8;

__device__ __forceinline__ ushort f2bf(float x) {   // RNE fp32 -> bf16
  unsigned u = __float_as_uint(x);
  u += 0x7fffu + ((u >> 16) & 1u);
  return (ushort)(u >> 16);
}

__device__ __forceinline__ unsigned pack2(ushort a, ushort b) {
  return (unsigned)a | ((unsigned)b << 16);
}

// ---------------- kernel 0: W -> MFMA-fragment order (W only) -------------
// Wt2[(((colt*16+kt)*16+rc)*4+q)*8+e] = bf16(W[kt*32+q*8+e][colt*16+rc])
__global__ __launch_bounds__(256) void prep_kernel(
    const float* __restrict__ Wa, const float* __restrict__ Ws,
    const float* __restrict__ Wst, ushort* __restrict__ Wt2)
{
  int fid = blockIdx.x * 256 + threadIdx.x;   // 21504 B-frags
  if (fid >= 21504) return;
  const int q = fid & 3, rc = (fid >> 2) & 15, kt = (fid >> 6) & 15, colt = fid >> 10;
  const int col = colt * 16 + rc;
  const int kbase = kt * 32 + q * 8;
  ushort h[8];
  #pragma unroll
  for (int e = 0; e < 8; ++e) {
    const int k = kbase + e;
    float v;
    if (col < 288)      v = Wa [(size_t)k * 288 + col];
    else if (col < 320) v = Ws [(size_t)k * 32  + (col - 288)];
    else                v = Wst[(size_t)k * 16  + (col - 320)];
    h[e] = f2bf(v);
  }
  uint4 o = make_uint4(pack2(h[0], h[1]), pack2(h[2], h[3]),
                       pack2(h[4], h[5]), pack2(h[6], h[7]));
  *(uint4*)(Wt2 + (size_t)fid * 8) = o;
}

// ---------------- kernel A: MFMA GEMM + softmax -> coef --------------------
// 129 blocks x 16 rows, 8 waves (512 thr). A-fragments staged block-locally
// in LDS (coalesced float4 reads + f2bf -> bit-identical fragments). B is
// pre-laid-out in global (L2-hot). Wave (kh, ng): kh owns k-tiles kh*8..,
// ng owns n-tiles {ng, ng+4, ...}. 1-deep pipeline, no barrier in k-loop;
// k-halves merge in LDS.
__global__ __launch_bounds__(512) void proj_kernel(
    const float* __restrict__ s_i,
    const ushort* __restrict__ Wt2,
    const int*   __restrict__ actions,
    float4*      __restrict__ coef)
{
  __shared__ __align__(16) ushort At[8192];   // A fragments: 16 kt x 16 rc x 4 q x 8e
  __shared__ float lg[16][346];               // stride 346: 2-way bank aliasing (free)

  const int tid  = threadIdx.x;
  const int wave = tid >> 6, lane = tid & 63;
  const int q = lane >> 4, rc = lane & 15;
  const int row0 = blockIdx.x * 16;

  // ---- stage A: 1024 fragment-units, 2 per thread (coalesced 32B reads)
  #pragma unroll
  for (int u = 0; u < 2; ++u) {
    const int uid = tid + u * 512;
    const int qq = uid & 3, rr = (uid >> 2) & 15, kt = uid >> 6;
    int row = row0 + rr; if (row > TT) row = TT;
    const float* src = s_i + (size_t)row * SS + kt * 32 + qq * 8;
    float4 v0 = *(const float4*)src;
    float4 v1 = *(const float4*)(src + 4);
    uint4 o = make_uint4(pack2(f2bf(v0.x), f2bf(v0.y)),
                         pack2(f2bf(v0.z), f2bf(v0.w)),
                         pack2(f2bf(v1.x), f2bf(v1.y)),
                         pack2(f2bf(v1.z), f2bf(v1.w)));
    *(uint4*)(At + (size_t)uid * 8) = o;
  }
  __syncthreads();

  const int kh = wave >> 2;                  // k-half
  const int ng = wave & 3;                   // n-group
  const int ntiles = (ng == 0) ? 6 : 5;
  const int kt0 = kh * 8;

  const ushort* aBase = At  + rc * 32 + q * 8;          // LDS
  const ushort* bBase = Wt2 + rc * 32 + q * 8;          // global (L2-hot)

  floatx4 acc[6];
  #pragma unroll
  for (int j = 0; j < 6; ++j) acc[j] = (floatx4)(0.f);

  bf16x8 aC, aN, bC[6], bN[6];

  // ---- prologue: load k-tile kt0 fragments
  aC = *(const bf16x8*)(aBase + kt0 * 512);
  #pragma unroll
  for (int j = 0; j < 6; ++j) {
    if (j < ntiles) {
      const int colt = ng + 4 * j;
      bC[j] = *(const bf16x8*)(bBase + (size_t)colt * 8192 + kt0 * 512);
    }
  }

  #pragma unroll
  for (int kk = 0; kk < 8; ++kk) {
    const int kt = kt0 + kk;
    // ---- issue next k-tile's loads (stay in flight under the MFMAs)
    if (kk < 7) {
      aN = *(const bf16x8*)(aBase + (kt + 1) * 512);
      #pragma unroll
      for (int j = 0; j < 6; ++j) {
        if (j < ntiles) {
          const int colt = ng + 4 * j;
          bN[j] = *(const bf16x8*)(bBase + (size_t)colt * 8192 + (kt + 1) * 512);
        }
      }
    }
    #pragma unroll
    for (int j = 0; j < 6; ++j) {
      if (j < ntiles)
        acc[j] = __builtin_amdgcn_mfma_f32_16x16x32_bf16(aC, bC[j], acc[j], 0, 0, 0);
    }
    // ---- rotate pipeline (full unroll -> pure register renames)
    aC = aN;
    #pragma unroll
    for (int j = 0; j < 6; ++j) {
      if (j < ntiles) bC[j] = bN[j];
    }
  }

  // ---- merge k-halves through LDS (C/D layout: row = q*4+reg, col = rc)
  if (kh == 0) {
    #pragma unroll
    for (int j = 0; j < 6; ++j) {
      if (j < ntiles) {
        const int colt = ng + 4 * j;
        #pragma unroll
        for (int reg = 0; reg < 4; ++reg)
          lg[q * 4 + reg][colt * 16 + rc] = acc[j][reg];
      }
    }
  }
  __syncthreads();
  if (kh == 1) {
    #pragma unroll
    for (int j = 0; j < 6; ++j) {
      if (j < ntiles) {
        const int colt = ng + 4 * j;
        #pragma unroll
        for (int reg = 0; reg < 4; ++reg)
          lg[q * 4 + reg][colt * 16 + rc] += acc[j][reg];
      }
    }
  }
  __syncthreads();

  // ---- softmax epilogue: 16 rows x 16 b, threads 0..255
  if (tid < 256) {
    const int r = tid >> 4, b = tid & 15;
    const int row = row0 + r;
    if (row < TT) {
      float m = -3.4e38f;
      #pragma unroll
      for (int a = 0; a < 18; ++a) m = fmaxf(m, lg[r][b * 18 + a]);
      float sum = 0.f;
      #pragma unroll
      for (int a = 0; a < 18; ++a) sum += __expf(lg[r][b * 18 + a] - m);
      int act = actions[row];
      float aprob = __expf(lg[r][b * 18 + act] - m) / sum;

      float x0 = lg[r][288 + 2 * b], x1 = lg[r][288 + 2 * b + 1];
      float mm = fmaxf(x0, x1);
      float e0 = __expf(x0 - mm), e1 = __expf(x1 - mm);
      float inv = 1.f / (e0 + e1);

      float ms = -3.4e38f;
      #pragma unroll
      for (int j = 0; j < 16; ++j) ms = fmaxf(ms, lg[r][320 + j]);
      float ssum = 0.f;
      #pragma unroll
      for (int j = 0; j < 16; ++j) ssum += __expf(lg[r][320 + j] - ms);
      float stp = __expf(lg[r][320 + b] - ms) / ssum;

      coef[(size_t)row * NB + b] = make_float4(e0 * inv, e1 * inv, stp, aprob);
    } else if (row == TT) {
      // virtual step 2048: A = I, "action" prob = stop0 prob of row T
      float x0 = lg[r][288 + 2 * b], x1 = lg[r][288 + 2 * b + 1];
      float mm = fmaxf(x0, x1);
      float e0 = __expf(x0 - mm), e1 = __expf(x1 - mm);
      coef[(size_t)TT * NB + b] = make_float4(1.f, 0.f, 0.f, e0 / (e0 + e1));
    }
  }
}

// ---------------- kernel B: pass1 — chunk transfer matrices + w-vectors ----
// 16 blocks x 64 threads (4 chains/block): spreads the 8 MB of coef-prefetch
// load traffic across 16 CUs' load pipes (fusing into 1 block was a 71 us
// regression -- one CU's L1 pipe became the bottleneck).
__global__ __launch_bounds__(64) void pass1_kernel(
    const float4* __restrict__ coef,
    float* __restrict__ Wws, float* __restrict__ Mws)
{
  const int chunk = blockIdx.x * 4 + (threadIdx.x >> 4);
  const int c = threadIdx.x & 15;
  const int i0 = chunk * CLEN + 1;

  float G[16];
  #pragma unroll
  for (int r = 0; r < 16; ++r) G[r] = (r == c) ? 1.f : 0.f;

  float4 cfA[16], cfB[16];
  #pragma unroll
  for (int r = 0; r < 16; ++r) cfA[r] = coef[(size_t)i0 * 16 + r];
  #pragma unroll
  for (int r = 0; r < 16; ++r) cfB[r] = coef[(size_t)(i0 + 1) * 16 + r];

#define P1BODY(CUR, NXT, J)                                                  \
  {                                                                          \
    if ((J) + 2 < CLEN) {                                                    \
      _Pragma("unroll")                                                      \
      for (int r = 0; r < 16; ++r)                                           \
        NXT[r] = coef[(size_t)(i0 + (J) + 2) * 16 + r];                      \
    }                                                                        \
    float ta = 0.f, tb = 0.f, tc = 0.f, td = 0.f;                            \
    _Pragma("unroll")                                                        \
    for (int r = 0; r < 4; ++r) {                                            \
      ta = fmaf(CUR[r].y,      G[r],      ta);                               \
      tb = fmaf(CUR[r + 4].y,  G[r + 4],  tb);                               \
      tc = fmaf(CUR[r + 8].y,  G[r + 8],  tc);                               \
      td = fmaf(CUR[r + 12].y, G[r + 12], td);                               \
    }                                                                        \
    float et = EPEN * ((ta + tb) + (tc + td));                               \
    _Pragma("unroll")                                                        \
    for (int r = 0; r < 16; ++r)                                             \
      G[r] = fmaf(CUR[r].x, G[r], CUR[r].z * et);                            \
    float wa = 0.f, wb = 0.f, wc = 0.f, wd = 0.f;                            \
    _Pragma("unroll")                                                        \
    for (int r = 0; r < 4; ++r) {                                            \
      wa = fmaf(CUR[r].w,      G[r],      wa);                               \
      wb = fmaf(CUR[r + 4].w,  G[r + 4],  wb);                               \
      wc = fmaf(CUR[r + 8].w,  G[r + 8],  wc);                               \
      wd = fmaf(CUR[r + 12].w, G[r + 12], wd);                               \
    }                                                                        \
    Wws[(size_t)(chunk * CLEN + (J)) * 16 + c] = (wa + wb) + (wc + wd);      \
  }

  for (int j = 0; j < CLEN; j += 2) {
    P1BODY(cfA, cfB, j);
    P1BODY(cfB, cfA, j + 1);
  }
#undef P1BODY

  #pragma unroll
  for (int r = 0; r < 16; ++r)
    Mws[chunk * 256 + r * 16 + c] = G[r];
}

// ---------------- kernel C: pass2 — two-phase chunk walk ------------------
// Phase 1 (wave 0 only): serial 16x16 matvec chain, quad layout l = 4r+g.
// Per chunk: FMA nest -> two quad_perm DPP adds -> five parallel
// ds_bpermute gathers -> per-lane exponent -> rescale. Depth-8 named-reg
// Mws prefetch covers HBM latency.
// Phase 2 (all 512 threads): 2048 log(w_j . p_chunk) terms in parallel.
__global__ __launch_bounds__(512) void pass2_kernel(
    const float4* __restrict__ coef,
    const float* __restrict__ Wws, const float* __restrict__ Mws,
    float* __restrict__ out)
{
  __shared__ float pbuf[NCHUNK][16];   // chunk-start scaled p vectors
  __shared__ float wacc[8];            // per-wave partial log sums

  const int tid = threadIdx.x;
  long long Ktot = 0;                  // only thread 0's value is used

  // ---------------- phase 1: serial chain, wave 0 only ----------------
  if (tid < 64) {
    const int r = tid >> 2, g = tid & 3;     // quad layout: lane = 4r+g
    float pj0 = coef[4 * g + 0].z;
    float pj1 = coef[4 * g + 1].z;
    float pj2 = coef[4 * g + 2].z;
    float pj3 = coef[4 * g + 3].z;

    const int moff = r * 16 + 4 * g;
    // bpermute byte addrs: y_{4g+j} lives in quad (4g+j) -> lane 16g+4j
    const int gb0 = 64 * g, gb1 = gb0 + 16, gb2 = gb0 + 32, gb3 = gb0 + 48;
    int Ecum = 0;

    // prefetch depth 8 (named regs; no runtime indexing -> no scratch)
    float4 mR0 = *(const float4*)&Mws[0 * 256 + moff];
    float4 mR1 = *(const float4*)&Mws[1 * 256 + moff];
    float4 mR2 = *(const float4*)&Mws[2 * 256 + moff];
    float4 mR3 = *(const float4*)&Mws[3 * 256 + moff];
    float4 mR4 = *(const float4*)&Mws[4 * 256 + moff];
    float4 mR5 = *(const float4*)&Mws[5 * 256 + moff];
    float4 mR6 = *(const float4*)&Mws[6 * 256 + moff];
    float4 mR7 = *(const float4*)&Mws[7 * 256 + moff];

#define P2BODY(K, MREG, KPF)                                                 \
    {                                                                        \
      if (r == 0)                                                            \
        *(float4*)&pbuf[(K)][4 * g] = make_float4(pj0, pj1, pj2, pj3);       \
      Ktot += 32LL * (long long)Ecum;                                        \
      float part = fmaf(MREG.x, pj0,                                         \
                   fmaf(MREG.y, pj1, fmaf(MREG.z, pj2, MREG.w * pj3)));      \
      if ((KPF) < NCHUNK)                                                    \
        MREG = *(const float4*)&Mws[(KPF) * 256 + moff];                     \
      /* quad rotate-add: lane g accumulates (Pg+Pg+1)+(Pg+2+Pg+3) */        \
      part += __int_as_float(__builtin_amdgcn_mov_dpp(                       \
          __float_as_int(part), 0x39, 0xF, 0xF, true));  /* quad ror 1 */    \
      part += __int_as_float(__builtin_amdgcn_mov_dpp(                       \
          __float_as_int(part), 0x4E, 0xF, 0xF, true));  /* quad ror 2 */    \
      int ip = __float_as_int(part);                                         \
      float n0 = __int_as_float(__builtin_amdgcn_ds_bpermute(gb0, ip));      \
      float n1 = __int_as_float(__builtin_amdgcn_ds_bpermute(gb1, ip));      \
      float n2 = __int_as_float(__builtin_amdgcn_ds_bpermute(gb2, ip));      \
      float n3 = __int_as_float(__builtin_amdgcn_ds_bpermute(gb3, ip));      \
      float y0 = __int_as_float(__builtin_amdgcn_ds_bpermute(0,   ip));      \
      int eb = (__float_as_int(y0) >> 23) & 255;                             \
      Ecum += eb - 127;                                                      \
      float sc = __int_as_float((254 - eb) << 23);                           \
      pj0 = n0 * sc; pj1 = n1 * sc; pj2 = n2 * sc; pj3 = n3 * sc;            \
    }

    for (int kb = 0; kb < NCHUNK; kb += 8) {
      P2BODY(kb + 0, mR0, kb + 8);
      P2BODY(kb + 1, mR1, kb + 9);
      P2BODY(kb + 2, mR2, kb + 10);
      P2BODY(kb + 3, mR3, kb + 11);
      P2BODY(kb + 4, mR4, kb + 12);
      P2BODY(kb + 5, mR5, kb + 13);
      P2BODY(kb + 6, mR6, kb + 14);
      P2BODY(kb + 7, mR7, kb + 15);
    }
#undef P2BODY
  }
  __syncthreads();

  // ---------------- phase 2: 2048 parallel log terms ----------------
  const int j0 = tid * 4;              // 4 consecutive steps, same chunk
  const int chunk = j0 >> 5;
  float p[16];
  #pragma unroll
  for (int c = 0; c < 16; ++c) p[c] = pbuf[chunk][c];

  float lacc = 0.f;
  #pragma unroll
  for (int jj = 0; jj < 4; ++jj) {
    const float* w = Wws + (size_t)(j0 + jj) * 16;
    float4 w0 = *(const float4*)(w);
    float4 w1 = *(const float4*)(w + 4);
    float4 w2 = *(const float4*)(w + 8);
    float4 w3 = *(const float4*)(w + 12);
    float s0 = fmaf(w0.x, p[0],  fmaf(w0.y, p[1],  fmaf(w0.z, p[2],  w0.w * p[3])));
    float s1 = fmaf(w1.x, p[4],  fmaf(w1.y, p[5],  fmaf(w1.z, p[6],  w1.w * p[7])));
    float s2 = fmaf(w2.x, p[8],  fmaf(w2.y, p[9],  fmaf(w2.z, p[10], w2.w * p[11])));
    float s3 = fmaf(w3.x, p[12], fmaf(w3.y, p[13], fmaf(w3.z, p[14], w3.w * p[15])));
    lacc += __logf((s0 + s1) + (s2 + s3));
  }

  if (tid == 0) {          // U0 term: sum_c coef[c].w * coef[c].z
    float U0 = 0.f;
    #pragma unroll
    for (int c = 0; c < 16; ++c) U0 = fmaf(coef[c].w, coef[c].z, U0);
    lacc += __logf(U0);
  }

  // wave reduce, then 8-entry double sum
  lacc += __shfl_xor(lacc, 1, 64);
  lacc += __shfl_xor(lacc, 2, 64);
  lacc += __shfl_xor(lacc, 4, 64);
  lacc += __shfl_xor(lacc, 8, 64);
  lacc += __shfl_xor(lacc, 16, 64);
  lacc += __shfl_xor(lacc, 32, 64);
  if ((tid & 63) == 0) wacc[tid >> 6] = lacc;
  __syncthreads();
  if (tid == 0) {
    double s = 0.0;
    #pragma unroll
    for (int i = 0; i < 8; ++i) s += (double)wacc[i];
    out[0] = (float)(s + 0.6931471805599453 * (double)Ktot);
  }
}

extern "C" void kernel_launch(void* const* d_in, const int* in_sizes, int n_in,
                              void* d_out, int out_size, void* d_ws, size_t ws_size,
                              hipStream_t stream) {
  const float* s_i = (const float*)d_in[0];
  const float* Wa  = (const float*)d_in[1];
  const float* Ws  = (const float*)d_in[2];
  const float* Wst = (const float*)d_in[3];
  const int*   act = (const int*)d_in[4];

  char* ws = (char*)d_ws;
  float4* coef = (float4*)ws;                        //   524,544 B
  float*  Wws  = (float*)(ws + 524544);              // + 131,072 B
  float*  Mws  = (float*)(ws + 524544 + 131072);     // +  65,536 B
  ushort* Wt2  = (ushort*)(ws + 721152);             // + 344,064 B (~1.0 MB)

  prep_kernel <<<84,  256, 0, stream>>>(Wa, Ws, Wst, Wt2);
  proj_kernel <<<129, 512, 0, stream>>>(s_i, Wt2, act, coef);
  pass1_kernel<<<16,  64,  0, stream>>>(coef, Wws, Mws);
  pass2_kernel<<<1,   512, 0, stream>>>(coef, Wws, Mws, (float*)d_out);
}